// Round 9
// baseline (1057.713 us; speedup 1.0000x reference)
//
#include <hip/hip_runtime.h>

// HiddenMarkovGFormulaV2: N independent sequential filters over T=64 steps.
// Memory-bound streaming problem (~362 MB HBM traffic w/ L3 reuse).
//
// v10 theory: v9 falsified the constant-write-drain model (occupancy 2x ->
// write path 1.09->1.21 TB/s) but gained only 12% because total
// outstanding bytes/CU stayed ~158 KB (halved burst x doubled waves) and
// flow stayed burst-drain-idle: every wave drains vmcnt to 0, computes
// ~3500 cycles memory-silent. v4 (only kernel with loads in flight DURING
// compute) had the best per-CU BW; copy ubench (continuous, never drains)
// gets 24.6 GB/s/CU vs our 8.6. v10 = continuity x occupancy:
//  * 2560 persistent 1-wave blocks (10/CU), each pipelines ~5 panels:
//    stage k -> ISSUE k+1 loads -> compute k -> store k. Next-panel loads
//    (24 KB/wave) stay in flight through the whole scan.
//  * No __syncthreads in the loop: wave-private LDS + asm lgkmcnt(0)
//    (v4-proven) -> no vmcnt(0) drains anywhere; stage waits pf regs via
//    counted vmcnt (stores + prefetch stay outstanding).
//  * S is BINARY (randint(0,2)) and C in [0,1): pack S->bit30, Y->bit31,
//    C->bits0..29 of ONE word (exact). Input = 1 LDS array; mean reuses
//    it after consumption; var = 2nd array -> LDS 16 KB, 10 blocks/CU,
//    no double buffer. Prefetch parks in regs (96 VGPR, ~145 live,
//    cap 170 via __launch_bounds__(64,3) -> no spill).
//  * Dense 1 KB/instruction global access + col = r^(t&31) swizzle
//    (<=2-way all phases) carried from v9. Step math identical v3..v9.

#define TT 64          // timesteps (fixed by reference)
#define KK 3           // covariates (fixed by reference)
#define NR 32          // rows per panel
#define BT 64          // threads per block (1 wave)
#define NBLK 2560      // persistent blocks = 256 CU x 10

__global__ __launch_bounds__(256) void ll_reduce_kernel(
    const float* __restrict__ part, float* __restrict__ ll_out, int nw)
{
    float s = 0.0f;
    for (int i = threadIdx.x; i < nw; i += 256) s += part[i];
    #pragma unroll
    for (int off = 32; off > 0; off >>= 1) s += __shfl_down(s, off, 64);
    __shared__ float ws[4];
    const int wid = threadIdx.x >> 6, lane = threadIdx.x & 63;
    if (lane == 0) ws[wid] = s;
    __syncthreads();
    if (threadIdx.x == 0) *ll_out = ws[0] + ws[1] + ws[2] + ws[3];
}

// pack S (binary), Y (binary), C (in [0,2): bit30,31 of bits(C) are 0):
// w = bits(C) | Y<<31 | S<<30. Exact & bijective.
// bits(1.0f)<<8 == 0x80000000 (Y); bit23 of 1.0f -> <<7 -> bit30 (S).
__device__ __forceinline__ float packSCY(float s, float c, float y) {
    const unsigned w = __float_as_uint(c)
                     | (__float_as_uint(y) << 8)
                     | ((__float_as_uint(s) & 0x00800000u) << 7);
    return __uint_as_float(w);
}

// Fill prefetch regs for panel PP: 24 dense dwordx4 + G/L row scalars.
#define LOAD_PANEL(PP)                                                    \
    {                                                                     \
        const int base_ = (PP) * NR;                                      \
        _Pragma("unroll")                                                 \
        for (int i_ = 0; i_ < 8; ++i_) {                                  \
            const int q_ = tid + i_ * BT;                                 \
            const int r_ = q_ >> 4, x_ = q_ & 15;                         \
            const int nn_ = base_ + r_;                                   \
            if (nn_ < N) {                                                \
                const int g_ = nn_ * (TT / 4) + x_;                       \
                pS[i_] = S4[g_]; pC[i_] = C4[g_]; pY[i_] = Y4[g_];        \
            } else {                                                      \
                pS[i_] = make_float4(0, 0, 0, 0);                         \
                pC[i_] = pS[i_]; pY[i_] = pS[i_];                         \
            }                                                             \
        }                                                                 \
        const int ng_ = base_ + rl;                                       \
        if (ng_ < N) {                                                    \
            gvn = G[ng_];                                                 \
            l0n = L[ng_ * KK + 0];                                        \
            l1n = L[ng_ * KK + 1];                                        \
            l2n = L[ng_ * KK + 2];                                        \
        } else {                                                          \
            gvn = 0.0f; l0n = 0.0f; l1n = 0.0f; l2n = 0.0f;               \
        }                                                                 \
    }

__global__ __launch_bounds__(BT, 3) void hmm_filter_kernel(
    const float* __restrict__ G,   // (N,1)
    const float* __restrict__ S,   // (N,T)
    const float* __restrict__ C,   // (N,T)
    const float* __restrict__ Y,   // (N,T)
    const float* __restrict__ L,   // (N,K)
    const float* __restrict__ p_psi,
    const float* __restrict__ p_gS,
    const float* __restrict__ p_gC,
    const float* __restrict__ p_gG,
    const float* __restrict__ p_gGS,
    const float* __restrict__ p_gGC,
    const float* __restrict__ p_gLw,  // (1,K)
    const float* __restrict__ p_lsZ,
    const float* __restrict__ p_b0,
    const float* __restrict__ p_bZ,
    const float* __restrict__ p_bS,
    const float* __restrict__ p_bG,
    const float* __restrict__ p_bGS,
    const float* __restrict__ p_bLw,  // (1,K)
    float* __restrict__ Zf,           // (N,T)
    float* __restrict__ Zv,           // (N,T)
    float* __restrict__ ll_part,      // one partial per block
    int N, int npanels)
{
    // [t][col], col = r ^ (t&31). sIM: packed input, then mean (each slot
    // consumed at step t, then overwritten). sV: var. 16,384 B exactly.
    __shared__ float sIM[TT][NR];
    __shared__ float sV [TT][NR];

    const int tid = threadIdx.x;      // 0..63 == lane
    const int rl  = tid & 31;         // row owned during the scan

    // --- uniform parameters (scalar-cached broadcast loads) ---
    const float psi  = p_psi[0];
    const float gS   = p_gS[0];
    const float gC   = p_gC[0];
    const float gG   = p_gG[0];
    const float gGS  = p_gGS[0];
    const float gGC  = p_gGC[0];
    const float b0   = p_b0[0];
    const float bZ   = p_bZ[0];
    const float bS   = p_bS[0];
    const float bG   = p_bG[0];
    const float bGS  = p_bGS[0];
    const float esz  = expf(p_lsZ[0]);
    const float sigma2 = esz * esz;
    const float psi2 = psi * psi;
    const float bZ2  = bZ * bZ;
    const float gw0 = p_gLw[0], gw1 = p_gLw[1], gw2 = p_gLw[2];
    const float bw0 = p_bLw[0], bw1 = p_bLw[1], bw2 = p_bLw[2];

    const float4* S4 = (const float4*)S;
    const float4* C4 = (const float4*)C;
    const float4* Y4 = (const float4*)Y;
    float4* Zf4 = (float4*)Zf;
    float4* Zv4 = (float4*)Zv;

    float4 pS[8], pC[8], pY[8];       // prefetch regs (96 VGPR)
    float gvn, l0n, l1n, l2n;         // prefetched G/L for owned row

    float ll_tot = 0.0f;              // log2-domain ll across panels

    int p = blockIdx.x;
    LOAD_PANEL(p);                    // prologue: panel 0 of this block

    while (true) {
        const int n0 = p * NR;

        // ---- stage packed panel k -> LDS (counted vmcnt on pf regs:
        //      outstanding stores/prefetch are NOT drained) ----
        #pragma unroll
        for (int i = 0; i < 8; ++i) {
            const int q = tid + i * BT;
            const int r = q >> 4, x = q & 15;
            const int t0 = x * 4;
            sIM[t0 + 0][r ^ ((t0 + 0) & 31)] = packSCY(pS[i].x, pC[i].x, pY[i].x);
            sIM[t0 + 1][r ^ ((t0 + 1) & 31)] = packSCY(pS[i].y, pC[i].y, pY[i].y);
            sIM[t0 + 2][r ^ ((t0 + 2) & 31)] = packSCY(pS[i].z, pC[i].z, pY[i].z);
            sIM[t0 + 3][r ^ ((t0 + 3) & 31)] = packSCY(pS[i].w, pC[i].w, pY[i].w);
        }

        // ---- per-row coefficients from prefetched G/L ----
        const int n = n0 + rl;
        const bool valid = (tid < 32) && (n < N);
        const float gL = l0n * gw0 + l1n * gw1 + l2n * gw2;
        const float bL = l0n * bw0 + l1n * bw1 + l2n * bw2;
        const float a_s   = gS + gGS * gvn;
        const float a_c   = gC + gGC * gvn;
        const float zbase = gG * gvn + gL;
        const float b_s   = bS + bGS * gvn;
        const float lbase = b0 + bG * gvn + bL;

        // ---- issue panel k+1 loads: in flight through the whole scan ----
        const int pn = p + gridDim.x;
        if (pn < npanels) LOAD_PANEL(pn);

        // stage writes visible to all lanes (DS only; vmcnt untouched)
        asm volatile("s_waitcnt lgkmcnt(0)" ::: "memory");

        // ---- sequential filter: lane rl owns row rl; lanes 32-63 read
        //      broadcast duplicates, masked off the LDS writes ----
        float zm = 0.0f, zv = 1.0f, ll2 = 0.0f;
        #pragma unroll
        for (int t = 0; t < TT; ++t) {
            const int col    = rl ^ (t & 31);   // lane perm: no conflict
            const unsigned w = __float_as_uint(sIM[t][col]);
            const float c    = __uint_as_float(w & 0x3FFFFFFFu);
            const float s    = (w & 0x40000000u) ? 1.0f : 0.0f;
            const bool  yb   = (w >> 31) != 0u;

            const float zpred = fmaf(psi, zm, fmaf(a_s, s, fmaf(a_c, c, zbase)));
            const float zpvar = fmaf(psi2, zv, sigma2);

            float logit = fmaf(bZ, zpred, fmaf(b_s, s, lbase));
            logit = fminf(fmaxf(logit, -20.0f), 20.0f);
            const float pr  = __builtin_amdgcn_rcpf(1.0f + __expf(-logit));
            const float omp = 1.0f - pr;

            const float ymp = yb ? omp : -pr;    // (y - p)
            const float sel = yb ? pr : omp;     // prob of observed outcome

            const float hess = fmaf(bZ2 * pr, omp, 1e-6f);
            const float zpostvar  = zpvar * __builtin_amdgcn_rcpf(fmaf(zpvar, hess, 1.0f));
            const float zpostmean = fmaf(zpostvar * bZ, ymp, zpred);

            ll2 += __log2f(sel + 1e-10f);

            zm = zpostmean;
            zv = zpostvar;
            if (tid < 32) {
                sIM[t][col] = zpostmean;   // mean reuses consumed input slot
                sV [t][col] = zpostvar;
            }
        }
        if (valid) ll_tot += ll2;

        // scan's ds_writes visible before cross-lane readback
        asm volatile("s_waitcnt lgkmcnt(0)" ::: "memory");

        // ---- dense stores (1024 B/instruction); fire-and-forget ----
        #pragma unroll
        for (int i = 0; i < 8; ++i) {
            const int q = tid + i * BT;
            const int r = q >> 4, x = q & 15;
            const int nn = n0 + r;
            if (nn < N) {
                const int t0 = x * 4;
                float4 vf, vv;
                vf.x = sIM[t0 + 0][r ^ ((t0 + 0) & 31)];
                vf.y = sIM[t0 + 1][r ^ ((t0 + 1) & 31)];
                vf.z = sIM[t0 + 2][r ^ ((t0 + 2) & 31)];
                vf.w = sIM[t0 + 3][r ^ ((t0 + 3) & 31)];
                vv.x = sV[t0 + 0][r ^ ((t0 + 0) & 31)];
                vv.y = sV[t0 + 1][r ^ ((t0 + 1) & 31)];
                vv.z = sV[t0 + 2][r ^ ((t0 + 2) & 31)];
                vv.w = sV[t0 + 3][r ^ ((t0 + 3) & 31)];
                const int g = nn * (TT / 4) + x;
                Zf4[g] = vf;
                Zv4[g] = vv;
            }
        }

        if (pn >= npanels) break;
        p = pn;
        // Next stage's ds_writes follow this phase's ds_reads in program
        // order; per-wave DS ops execute in order -> WAR safe, no wait.
    }

    // ---- ll reduction: wave shuffle -> one partial per block ----
    float ll = ll_tot * 0.69314718055994531f;
    #pragma unroll
    for (int off = 32; off > 0; off >>= 1) {
        ll += __shfl_down(ll, off, 64);
    }
    if (tid == 0) ll_part[blockIdx.x] = ll;
}

extern "C" void kernel_launch(void* const* d_in, const int* in_sizes, int n_in,
                              void* d_out, int out_size, void* d_ws, size_t ws_size,
                              hipStream_t stream) {
    const int N = in_sizes[0];  // G is (N,1)

    const float* G   = (const float*)d_in[0];
    const float* S   = (const float*)d_in[1];
    const float* C   = (const float*)d_in[2];
    const float* Y   = (const float*)d_in[3];
    const float* L   = (const float*)d_in[4];
    const float* psi = (const float*)d_in[5];
    const float* gS  = (const float*)d_in[6];
    const float* gC  = (const float*)d_in[7];
    const float* gG  = (const float*)d_in[8];
    const float* gGS = (const float*)d_in[9];
    const float* gGC = (const float*)d_in[10];
    const float* gLw = (const float*)d_in[11];
    const float* lsZ = (const float*)d_in[12];
    const float* b0  = (const float*)d_in[13];
    const float* bZ  = (const float*)d_in[14];
    const float* bS  = (const float*)d_in[15];
    const float* bG  = (const float*)d_in[16];
    const float* bGS = (const float*)d_in[17];
    const float* bLw = (const float*)d_in[18];

    float* out = (float*)d_out;
    float* Zf = out;
    float* Zv = out + (size_t)N * TT;
    float* ll = out + (size_t)2 * N * TT;

    float* ll_part = (float*)d_ws;   // one float per block of workspace

    const int npanels = (N + NR - 1) / NR;
    const int blocks  = (npanels < NBLK) ? npanels : NBLK;
    hmm_filter_kernel<<<blocks, BT, 0, stream>>>(
        G, S, C, Y, L, psi, gS, gC, gG, gGS, gGC, gLw, lsZ,
        b0, bZ, bS, bG, bGS, bLw, Zf, Zv, ll_part, N, npanels);
    ll_reduce_kernel<<<1, 256, 0, stream>>>(ll_part, ll, blocks);
}

// Round 10
// 456.802 us; speedup vs baseline: 2.3155x; 2.3155x over previous
//
#include <hip/hip_runtime.h>

// HiddenMarkovGFormulaV2: N independent sequential filters over T=64 steps.
// Memory-bound streaming problem (~362 MB HBM traffic w/ L3 reuse).
//
// v11 = v10's persistent-pipelined design, with the register budget it
// actually needs. v10 failed ONLY by spill: launch_bounds(64,3) capped
// VGPR at 170 < ~190 live -> prefetch array spilled to scratch (VGPR=84,
// WRITE 546 MB = +346 MB scratch, 750 us). The duty-cycle model survives:
// v9's 10 phase-locked waves burst 240 KB then sit memory-silent for the
// ~4200-cycle scan (per-step dependency chain ~65 cyc: 3 dep fmaf + exp +
// 2 rcp) -> memory duty ~30% -> 2.2 TB/s observed.
//
// v11 changes vs v10:
//  * __launch_bounds__(64, 2): VGPR cap 256 >= ~190 live -> NO spill.
//    Occupancy: VGPR-bound 2 waves/SIMD = 8/CU; grid = 2048 (8/CU).
//  * Scan loop unroll 8 (not 64): smaller scheduling window, defends
//    against the allocator heuristic that collapsed v10 to 84 VGPR.
//  * Everything else identical to v10 (which was v9's proven math +
//    panel pipeline): persistent 1-wave blocks; stage k -> issue k+1's
//    24 dense dwordx4 loads (in flight through the whole scan) -> scan k
//    -> store k; no vmcnt(0) drains (wave-private LDS, asm lgkmcnt only);
//    S->bit30/Y->bit31/C->bits0..29 packed single-word LDS (16 KB total,
//    input slot reused by mean); dense 1 KB/instruction global access;
//    col = r^(t&31) swizzle (<=2-way all LDS phases).
//  * Step math identical v3..v10 (passed, absmax 0.0078125).

#define TT 64          // timesteps (fixed by reference)
#define KK 3           // covariates (fixed by reference)
#define NR 32          // rows per panel
#define BT 64          // threads per block (1 wave)
#define NBLK 2048      // persistent blocks = 256 CU x 8 (VGPR-bound)

__global__ __launch_bounds__(256) void ll_reduce_kernel(
    const float* __restrict__ part, float* __restrict__ ll_out, int nw)
{
    float s = 0.0f;
    for (int i = threadIdx.x; i < nw; i += 256) s += part[i];
    #pragma unroll
    for (int off = 32; off > 0; off >>= 1) s += __shfl_down(s, off, 64);
    __shared__ float ws[4];
    const int wid = threadIdx.x >> 6, lane = threadIdx.x & 63;
    if (lane == 0) ws[wid] = s;
    __syncthreads();
    if (threadIdx.x == 0) *ll_out = ws[0] + ws[1] + ws[2] + ws[3];
}

// pack S (binary), Y (binary), C (in [0,1)): w = bits(C) | Y<<31 | S<<30.
// Exact: bits(1.0f)<<8 == 0x80000000 (Y); bit23 of 1.0f <<7 -> bit30 (S);
// bits(C) for C in [0,1) never touches bits 30/31.
__device__ __forceinline__ float packSCY(float s, float c, float y) {
    const unsigned w = __float_as_uint(c)
                     | (__float_as_uint(y) << 8)
                     | ((__float_as_uint(s) & 0x00800000u) << 7);
    return __uint_as_float(w);
}

// Fill prefetch regs for panel PP: 24 dense dwordx4 + G/L row scalars.
#define LOAD_PANEL(PP)                                                    \
    {                                                                     \
        const int base_ = (PP) * NR;                                      \
        _Pragma("unroll")                                                 \
        for (int i_ = 0; i_ < 8; ++i_) {                                  \
            const int q_ = tid + i_ * BT;                                 \
            const int r_ = q_ >> 4, x_ = q_ & 15;                         \
            const int nn_ = base_ + r_;                                   \
            if (nn_ < N) {                                                \
                const int g_ = nn_ * (TT / 4) + x_;                       \
                pS[i_] = S4[g_]; pC[i_] = C4[g_]; pY[i_] = Y4[g_];        \
            } else {                                                      \
                pS[i_] = make_float4(0, 0, 0, 0);                         \
                pC[i_] = pS[i_]; pY[i_] = pS[i_];                         \
            }                                                             \
        }                                                                 \
        const int ng_ = base_ + rl;                                       \
        if (ng_ < N) {                                                    \
            gvn = G[ng_];                                                 \
            l0n = L[ng_ * KK + 0];                                        \
            l1n = L[ng_ * KK + 1];                                        \
            l2n = L[ng_ * KK + 2];                                        \
        } else {                                                          \
            gvn = 0.0f; l0n = 0.0f; l1n = 0.0f; l2n = 0.0f;               \
        }                                                                 \
    }

__global__ __launch_bounds__(BT, 2) void hmm_filter_kernel(
    const float* __restrict__ G,   // (N,1)
    const float* __restrict__ S,   // (N,T)
    const float* __restrict__ C,   // (N,T)
    const float* __restrict__ Y,   // (N,T)
    const float* __restrict__ L,   // (N,K)
    const float* __restrict__ p_psi,
    const float* __restrict__ p_gS,
    const float* __restrict__ p_gC,
    const float* __restrict__ p_gG,
    const float* __restrict__ p_gGS,
    const float* __restrict__ p_gGC,
    const float* __restrict__ p_gLw,  // (1,K)
    const float* __restrict__ p_lsZ,
    const float* __restrict__ p_b0,
    const float* __restrict__ p_bZ,
    const float* __restrict__ p_bS,
    const float* __restrict__ p_bG,
    const float* __restrict__ p_bGS,
    const float* __restrict__ p_bLw,  // (1,K)
    float* __restrict__ Zf,           // (N,T)
    float* __restrict__ Zv,           // (N,T)
    float* __restrict__ ll_part,      // one partial per block
    int N, int npanels)
{
    // [t][col], col = r ^ (t&31). sIM: packed input, then mean (each slot
    // consumed at step t, then overwritten). sV: var. 16,384 B exactly.
    __shared__ float sIM[TT][NR];
    __shared__ float sV [TT][NR];

    const int tid = threadIdx.x;      // 0..63 == lane
    const int rl  = tid & 31;         // row owned during the scan

    // --- uniform parameters (scalar-cached broadcast loads) ---
    const float psi  = p_psi[0];
    const float gS   = p_gS[0];
    const float gC   = p_gC[0];
    const float gG   = p_gG[0];
    const float gGS  = p_gGS[0];
    const float gGC  = p_gGC[0];
    const float b0   = p_b0[0];
    const float bZ   = p_bZ[0];
    const float bS   = p_bS[0];
    const float bG   = p_bG[0];
    const float bGS  = p_bGS[0];
    const float esz  = expf(p_lsZ[0]);
    const float sigma2 = esz * esz;
    const float psi2 = psi * psi;
    const float bZ2  = bZ * bZ;
    const float gw0 = p_gLw[0], gw1 = p_gLw[1], gw2 = p_gLw[2];
    const float bw0 = p_bLw[0], bw1 = p_bLw[1], bw2 = p_bLw[2];

    const float4* S4 = (const float4*)S;
    const float4* C4 = (const float4*)C;
    const float4* Y4 = (const float4*)Y;
    float4* Zf4 = (float4*)Zf;
    float4* Zv4 = (float4*)Zv;

    float4 pS[8], pC[8], pY[8];       // prefetch regs (96 VGPR)
    float gvn, l0n, l1n, l2n;         // prefetched G/L for owned row

    float ll_tot = 0.0f;              // log2-domain ll across panels

    int p = blockIdx.x;
    LOAD_PANEL(p);                    // prologue: panel 0 of this block

    while (true) {
        const int n0 = p * NR;

        // ---- stage packed panel k -> LDS (counted vmcnt on pf regs:
        //      outstanding stores are NOT drained) ----
        #pragma unroll
        for (int i = 0; i < 8; ++i) {
            const int q = tid + i * BT;
            const int r = q >> 4, x = q & 15;
            const int t0 = x * 4;
            sIM[t0 + 0][r ^ ((t0 + 0) & 31)] = packSCY(pS[i].x, pC[i].x, pY[i].x);
            sIM[t0 + 1][r ^ ((t0 + 1) & 31)] = packSCY(pS[i].y, pC[i].y, pY[i].y);
            sIM[t0 + 2][r ^ ((t0 + 2) & 31)] = packSCY(pS[i].z, pC[i].z, pY[i].z);
            sIM[t0 + 3][r ^ ((t0 + 3) & 31)] = packSCY(pS[i].w, pC[i].w, pY[i].w);
        }

        // ---- per-row coefficients from prefetched G/L ----
        const int n = n0 + rl;
        const bool valid = (tid < 32) && (n < N);
        const float gL = l0n * gw0 + l1n * gw1 + l2n * gw2;
        const float bL = l0n * bw0 + l1n * bw1 + l2n * bw2;
        const float a_s   = gS + gGS * gvn;
        const float a_c   = gC + gGC * gvn;
        const float zbase = gG * gvn + gL;
        const float b_s   = bS + bGS * gvn;
        const float lbase = b0 + bG * gvn + bL;

        // ---- issue panel k+1 loads: in flight through the whole scan ----
        const int pn = p + gridDim.x;
        if (pn < npanels) LOAD_PANEL(pn);

        // stage writes visible to all lanes (DS only; vmcnt untouched)
        asm volatile("s_waitcnt lgkmcnt(0)" ::: "memory");

        // ---- sequential filter: lane rl owns row rl; lanes 32-63 read
        //      broadcast duplicates, masked off the LDS writes ----
        float zm = 0.0f, zv = 1.0f, ll2 = 0.0f;
        #pragma unroll 8
        for (int t = 0; t < TT; ++t) {
            const int col    = rl ^ (t & 31);   // lane perm: no conflict
            const unsigned w = __float_as_uint(sIM[t][col]);
            const float c    = __uint_as_float(w & 0x3FFFFFFFu);
            const float s    = (w & 0x40000000u) ? 1.0f : 0.0f;
            const bool  yb   = (w >> 31) != 0u;

            const float zpred = fmaf(psi, zm, fmaf(a_s, s, fmaf(a_c, c, zbase)));
            const float zpvar = fmaf(psi2, zv, sigma2);

            float logit = fmaf(bZ, zpred, fmaf(b_s, s, lbase));
            logit = fminf(fmaxf(logit, -20.0f), 20.0f);
            const float pr  = __builtin_amdgcn_rcpf(1.0f + __expf(-logit));
            const float omp = 1.0f - pr;

            const float ymp = yb ? omp : -pr;    // (y - p)
            const float sel = yb ? pr : omp;     // prob of observed outcome

            const float hess = fmaf(bZ2 * pr, omp, 1e-6f);
            const float zpostvar  = zpvar * __builtin_amdgcn_rcpf(fmaf(zpvar, hess, 1.0f));
            const float zpostmean = fmaf(zpostvar * bZ, ymp, zpred);

            ll2 += __log2f(sel + 1e-10f);

            zm = zpostmean;
            zv = zpostvar;
            if (tid < 32) {
                sIM[t][col] = zpostmean;   // mean reuses consumed input slot
                sV [t][col] = zpostvar;
            }
        }
        if (valid) ll_tot += ll2;

        // scan's ds_writes visible before cross-lane readback
        asm volatile("s_waitcnt lgkmcnt(0)" ::: "memory");

        // ---- dense stores (1024 B/instruction); fire-and-forget ----
        #pragma unroll
        for (int i = 0; i < 8; ++i) {
            const int q = tid + i * BT;
            const int r = q >> 4, x = q & 15;
            const int nn = n0 + r;
            if (nn < N) {
                const int t0 = x * 4;
                float4 vf, vv;
                vf.x = sIM[t0 + 0][r ^ ((t0 + 0) & 31)];
                vf.y = sIM[t0 + 1][r ^ ((t0 + 1) & 31)];
                vf.z = sIM[t0 + 2][r ^ ((t0 + 2) & 31)];
                vf.w = sIM[t0 + 3][r ^ ((t0 + 3) & 31)];
                vv.x = sV[t0 + 0][r ^ ((t0 + 0) & 31)];
                vv.y = sV[t0 + 1][r ^ ((t0 + 1) & 31)];
                vv.z = sV[t0 + 2][r ^ ((t0 + 2) & 31)];
                vv.w = sV[t0 + 3][r ^ ((t0 + 3) & 31)];
                const int g = nn * (TT / 4) + x;
                Zf4[g] = vf;
                Zv4[g] = vv;
            }
        }

        if (pn >= npanels) break;
        p = pn;
        // Next stage's ds_writes follow this phase's ds_reads in program
        // order; per-wave DS ops execute in order -> WAR safe, no wait.
    }

    // ---- ll reduction: wave shuffle -> one partial per block ----
    float ll = ll_tot * 0.69314718055994531f;
    #pragma unroll
    for (int off = 32; off > 0; off >>= 1) {
        ll += __shfl_down(ll, off, 64);
    }
    if (tid == 0) ll_part[blockIdx.x] = ll;
}

extern "C" void kernel_launch(void* const* d_in, const int* in_sizes, int n_in,
                              void* d_out, int out_size, void* d_ws, size_t ws_size,
                              hipStream_t stream) {
    const int N = in_sizes[0];  // G is (N,1)

    const float* G   = (const float*)d_in[0];
    const float* S   = (const float*)d_in[1];
    const float* C   = (const float*)d_in[2];
    const float* Y   = (const float*)d_in[3];
    const float* L   = (const float*)d_in[4];
    const float* psi = (const float*)d_in[5];
    const float* gS  = (const float*)d_in[6];
    const float* gC  = (const float*)d_in[7];
    const float* gG  = (const float*)d_in[8];
    const float* gGS = (const float*)d_in[9];
    const float* gGC = (const float*)d_in[10];
    const float* gLw = (const float*)d_in[11];
    const float* lsZ = (const float*)d_in[12];
    const float* b0  = (const float*)d_in[13];
    const float* bZ  = (const float*)d_in[14];
    const float* bS  = (const float*)d_in[15];
    const float* bG  = (const float*)d_in[16];
    const float* bGS = (const float*)d_in[17];
    const float* bLw = (const float*)d_in[18];

    float* out = (float*)d_out;
    float* Zf = out;
    float* Zv = out + (size_t)N * TT;
    float* ll = out + (size_t)2 * N * TT;

    float* ll_part = (float*)d_ws;   // one float per block of workspace

    const int npanels = (N + NR - 1) / NR;
    const int blocks  = (npanels < NBLK) ? npanels : NBLK;
    hmm_filter_kernel<<<blocks, BT, 0, stream>>>(
        G, S, C, Y, L, psi, gS, gC, gG, gGS, gGC, gLw, lsZ,
        b0, bZ, bS, bG, bGS, bLw, Zf, Zv, ll_part, N, npanels);
    ll_reduce_kernel<<<1, 256, 0, stream>>>(ll_part, ll, blocks);
}